// Round 11
// baseline (214.572 us; speedup 1.0000x reference)
//
#include <hip/hip_runtime.h>

#define BB 2
#define NN 16384
#define MM 4096
#define C1 128
#define C2 256
#define CF 384    // C1+C2
#define CG 1024
#define CT 1411   // 3 + 384 + 1024
#define FLTMAX 3.402823466e+38f

#define NB   512               // x-bins
#define XLO  (-4.5f)
#define DXF  0.017578125f      // 9/512, exact in binary
#define INVDX 56.888888889f    // 512/9
#define NSPL 32                // stage-B splits (waves) per query group
#define WA   2048              // stage-A window points (8 waves x 256)

// ---------------- fallback (round-1) kernel ----------------
__global__ __launch_bounds__(256) void p2p_fused(
    const float* __restrict__ P, const float* __restrict__ Q,
    const float* __restrict__ F1, const float* __restrict__ F2,
    const float* __restrict__ G, float* __restrict__ out)
{
    const int t  = threadIdx.x;
    const int bm = blockIdx.x;
    const int b  = bm >> 12;
    const int m  = bm & (MM - 1);

    const float* Pb = P + (size_t)b * 3 * NN;
    const float qx = Q[(size_t)b * 3 * MM + 0 * MM + m];
    const float qy = Q[(size_t)b * 3 * MM + 1 * MM + m];
    const float qz = Q[(size_t)b * 3 * MM + 2 * MM + m];
    const float q2 = __fadd_rn(__fadd_rn(__fmul_rn(qx, qx), __fmul_rn(qy, qy)),
                               __fmul_rn(qz, qz));

    float bd0 = FLTMAX, bd1 = FLTMAX, bd2 = FLTMAX;
    int   bi0 = 0x7fffffff, bi1 = 0x7fffffff, bi2 = 0x7fffffff;

    for (int n = t; n < NN; n += 256) {
        float px = Pb[n];
        float py = Pb[NN + n];
        float pz = Pb[2 * NN + n];
        float p2 = __fadd_rn(__fadd_rn(__fmul_rn(px, px), __fmul_rn(py, py)),
                             __fmul_rn(pz, pz));
        float qp = __fadd_rn(__fadd_rn(__fmul_rn(qx, px), __fmul_rn(qy, py)),
                             __fmul_rn(qz, pz));
        float d2 = __fsub_rn(__fadd_rn(q2, p2), __fadd_rn(qp, qp));
        if (d2 < bd2) {
            if (d2 < bd1) {
                if (d2 < bd0) { bd2 = bd1; bi2 = bi1; bd1 = bd0; bi1 = bi0; bd0 = d2; bi0 = n; }
                else          { bd2 = bd1; bi2 = bi1; bd1 = d2;  bi1 = n; }
            } else            { bd2 = d2;  bi2 = n; }
        }
    }

    __shared__ float sd[256][3];
    __shared__ int   si[256][3];
    sd[t][0] = bd0; sd[t][1] = bd1; sd[t][2] = bd2;
    si[t][0] = bi0; si[t][1] = bi1; si[t][2] = bi2;
    __syncthreads();

    for (int off = 128; off >= 1; off >>= 1) {
        if (t < off) {
            float A[3]  = { sd[t][0], sd[t][1], sd[t][2] };
            int   AI[3] = { si[t][0], si[t][1], si[t][2] };
            float Bv[3] = { sd[t + off][0], sd[t + off][1], sd[t + off][2] };
            int   BI[3] = { si[t + off][0], si[t + off][1], si[t + off][2] };
            float rd[3]; int ri[3];
            int pa = 0, pb = 0;
            #pragma unroll
            for (int r = 0; r < 3; r++) {
                bool ta = (A[pa] < Bv[pb]) || (A[pa] == Bv[pb] && AI[pa] < BI[pb]);
                if (ta) { rd[r] = A[pa];  ri[r] = AI[pa]; pa++; }
                else    { rd[r] = Bv[pb]; ri[r] = BI[pb]; pb++; }
            }
            sd[t][0] = rd[0]; sd[t][1] = rd[1]; sd[t][2] = rd[2];
            si[t][0] = ri[0]; si[t][1] = ri[1]; si[t][2] = ri[2];
        }
        __syncthreads();
    }

    __shared__ float wsh[3];
    __shared__ int   ish[3];
    __shared__ float agg[CT + 1];

    if (t == 0) {
        float w[3];
        #pragma unroll
        for (int k = 0; k < 3; k++) {
            int i = si[0][k];
            ish[k] = i;
            float dx = __fsub_rn(Pb[i],          qx);
            float dy = __fsub_rn(Pb[NN + i],     qy);
            float dz = __fsub_rn(Pb[2 * NN + i], qz);
            float ds = __fadd_rn(__fadd_rn(__fmul_rn(dx, dx), __fmul_rn(dy, dy)),
                                 __fmul_rn(dz, dz));
            w[k] = expf(-0.5f * ds);
        }
        float Z = __fadd_rn(__fadd_rn(w[0], w[1]), w[2]);
        wsh[0] = w[0] / Z; wsh[1] = w[1] / Z; wsh[2] = w[2] / Z;
    }
    __syncthreads();

    const int   i0 = ish[0], i1 = ish[1], i2 = ish[2];
    const float w0 = wsh[0], w1 = wsh[1], w2 = wsh[2];

    if (t < 3) agg[t] = (t == 0) ? qx : ((t == 1) ? qy : qz);

    for (int c = t; c < C1 + C2; c += 256) {
        const float* base = (c < C1)
            ? (F1 + ((size_t)b * C1 + c) * NN)
            : (F2 + ((size_t)b * C2 + (c - C1)) * NN);
        float f0 = base[i0], f1 = base[i1], f2 = base[i2];
        float v = __fadd_rn(__fadd_rn(__fmul_rn(f0, w0), __fmul_rn(f1, w1)),
                            __fmul_rn(f2, w2));
        agg[3 + c] = v;
    }
    for (int c = t; c < CG; c += 256) {
        agg[3 + C1 + C2 + c] = G[(size_t)b * CG + c];
    }
    __syncthreads();

    float* orow = out + ((size_t)b * MM + m) * MM;
    for (int j = t; j < MM; j += 256) {
        int s = (j * CT) >> 12;
        int e = ((j + 1) * CT + (MM - 1)) >> 12;
        float v = agg[s];
        if (e - s > 1) v = fmaxf(v, agg[s + 1]);
        orow[j] = v;
    }
}

__device__ __forceinline__ int xbin(float x) {
    int ib = (int)floorf((x - XLO) * INVDX);
    return (ib < 0) ? 0 : ((ib > NB - 1) ? NB - 1 : ib);
}

// register-file broadcast: lane u's value -> all lanes (exact bit transport)
__device__ __forceinline__ float bcastf(float v, int u) {
    return __int_as_float(__builtin_amdgcn_readlane(__float_as_int(v), u));
}

// ---------------- kernel 1: histograms + pg row ----------------
__global__ __launch_bounds__(256) void k_hist(
    const float* __restrict__ P, const float* __restrict__ Q,
    const float* __restrict__ G,
    int* __restrict__ phist, int* __restrict__ qhist, float* __restrict__ pg)
{
    const int bid = blockIdx.x;
    const int t   = threadIdx.x;
    if (bid < 128) {
        int gid = bid * 256 + t;              // BB*NN
        int b = gid >> 14, n = gid & (NN - 1);
        atomicAdd(&phist[b * NB + xbin(P[(size_t)b * 3 * NN + n])], 1);
    } else if (bid < 160) {
        int gid = (bid - 128) * 256 + t;      // BB*MM
        int b = gid >> 12, m = gid & (MM - 1);
        atomicAdd(&qhist[b * NB + xbin(Q[(size_t)b * 3 * MM + m])], 1);
    } else {
        int gid = (bid - 160) * 256 + t;
        int b  = gid / 2972;
        int jj = gid % 2972;
        if (b < BB) {
            int j = 1124 + jj;
            int s = (j * CT) >> 12;
            int e = ((j + 1) * CT + (MM - 1)) >> 12;
            float v = G[(size_t)b * CG + (s - 387)];
            if (e - s > 1) v = fmaxf(v, G[(size_t)b * CG + (s - 386)]);
            pg[(size_t)b * MM + j] = v;
        }
    }
}

// ---------------- kernel 2: prefix scans -> binst, pcur, qcur -------------
__global__ __launch_bounds__(512) void k_scan(
    const int* __restrict__ phist, const int* __restrict__ qhist,
    int* __restrict__ binst, int* __restrict__ pcur, int* __restrict__ qcur)
{
    __shared__ int s[NB];
    const int b = blockIdx.x;
    const int t = threadIdx.x;

    s[t] = phist[b * NB + t];
    __syncthreads();
    for (int d = 1; d < NB; d <<= 1) {
        int v = (t >= d) ? s[t - d] : 0;
        __syncthreads();
        s[t] += v;
        __syncthreads();
    }
    int excl = s[t] - phist[b * NB + t];
    binst[b * (NB + 1) + t] = excl;
    pcur[b * NB + t] = excl;
    if (t == 0) binst[b * (NB + 1) + NB] = NN;
    __syncthreads();

    s[t] = qhist[b * NB + t];
    __syncthreads();
    for (int d = 1; d < NB; d <<= 1) {
        int v = (t >= d) ? s[t - d] : 0;
        __syncthreads();
        s[t] += v;
        __syncthreads();
    }
    qcur[b * NB + t] = s[t] - qhist[b * NB + t];
}

// ---------------- kernel 3: scatter (points + queries) --------------------
__global__ __launch_bounds__(256) void k_scatter(
    const float* __restrict__ P, const float* __restrict__ Q,
    int* __restrict__ pcur, int* __restrict__ qcur,
    float4* __restrict__ P4s, int* __restrict__ idxs, int* __restrict__ qperm)
{
    const int bid = blockIdx.x;
    const int t   = threadIdx.x;
    if (bid < 128) {
        int gid = bid * 256 + t;
        int b = gid >> 14, n = gid & (NN - 1);
        const float* Pb = P + (size_t)b * 3 * NN;
        float x = Pb[n], y = Pb[NN + n], z = Pb[2 * NN + n];
        float p2 = __fadd_rn(__fadd_rn(__fmul_rn(x, x), __fmul_rn(y, y)),
                             __fmul_rn(z, z));
        int pos = atomicAdd(&pcur[b * NB + xbin(x)], 1);
        P4s[(size_t)b * NN + pos]  = make_float4(x, y, z, p2);
        idxs[(size_t)b * NN + pos] = n;
    } else {
        int gid = (bid - 128) * 256 + t;
        int b = gid >> 12, m = gid & (MM - 1);
        int pos = atomicAdd(&qcur[b * NB + xbin(Q[(size_t)b * 3 * MM + m])], 1);
        qperm[b * MM + pos] = m;
    }
}

// exact-rn distance from broadcast components (identical rounding to np ref)
__device__ __forceinline__ float dist_c(float qx, float qy, float qz, float q2,
                                        float px, float py, float pz, float pw)
{
    float qp = __fadd_rn(__fadd_rn(__fmul_rn(qx, px), __fmul_rn(qy, py)),
                         __fmul_rn(qz, pz));
    return __fsub_rn(__fadd_rn(q2, pw), __fadd_rn(qp, qp));
}

// value-only branchless 3-min insert (for ub computation)
#define INSV(dv)                                                             \
    {                                                                        \
        bool c0 = (dv) < b0, c1 = (dv) < b1, c2 = (dv) < b2;                 \
        float nb2 = c1 ? b1 : (c2 ? (dv) : b2);                              \
        float nb1 = c0 ? b0 : (c1 ? (dv) : b1);                              \
        float nb0 = c0 ? (dv) : b0;                                          \
        b0 = nb0; b1 = nb1; b2 = nb2;                                        \
    }

// lexicographic (d, idx) branchless insert — order-independent == top_k
#define INSL(dv, nv)                                                         \
    {                                                                        \
        bool c0 = ((dv) < b0) || ((dv) == b0 && (nv) < i0);                  \
        bool c1 = ((dv) < b1) || ((dv) == b1 && (nv) < i1);                  \
        bool c2 = ((dv) < b2) || ((dv) == b2 && (nv) < i2);                  \
        float nb2 = c1 ? b1 : (c2 ? (dv) : b2);                              \
        int   ni2 = c1 ? i1 : (c2 ? (nv) : i2);                              \
        float nb1 = c0 ? b0 : (c1 ? (dv) : b1);                              \
        int   ni1 = c0 ? i0 : (c1 ? (nv) : i1);                              \
        float nb0 = c0 ? (dv) : b0;                                          \
        int   ni0 = c0 ? (nv) : i0;                                          \
        b0 = nb0; b1 = nb1; b2 = nb2; i0 = ni0; i1 = ni1; i2 = ni2;          \
    }

// ---------------- kernel 4: stage A — window ub + group range -------------
// 128 blocks x 512 (8 waves). Tile64 + readlane broadcast point stream.
__global__ __launch_bounds__(512) void stageA(
    const float4* __restrict__ P4s, const int* __restrict__ binst,
    const int* __restrict__ qperm, const float* __restrict__ Q,
    int2* __restrict__ grange)
{
    __shared__ float sdm[8 * 64 * 3];
    const int t    = threadIdx.x;
    const int lane = t & 63;
    const int wv   = t >> 6;              // 0..7
    const int g    = blockIdx.x;          // 0..127
    const int b    = g >> 6;
    const int gl   = g & 63;

    const int qi = qperm[b * MM + gl * 64 + lane];
    const float qx = Q[(size_t)b * 3 * MM + qi];
    const float qy = Q[(size_t)b * 3 * MM + MM + qi];
    const float qz = Q[(size_t)b * 3 * MM + 2 * MM + qi];
    const float q2 = __fadd_rn(__fadd_rn(__fmul_rn(qx, qx), __fmul_rn(qy, qy)),
                               __fmul_rn(qz, qz));

    const float4* Ps = P4s + (size_t)b * NN;
    const int*    Bs = binst + b * (NB + 1);

    int ib = xbin(qx);
    int bmin = ib, bmax = ib;
    #pragma unroll
    for (int mask = 1; mask < 64; mask <<= 1) {
        bmin = min(bmin, __shfl_xor(bmin, mask));
        bmax = max(bmax, __shfl_xor(bmax, mask));
    }
    bmin = __builtin_amdgcn_readfirstlane(bmin);
    bmax = __builtin_amdgcn_readfirstlane(bmax);
    int ctr = (Bs[bmin] + Bs[bmax + 1]) >> 1;
    int wlo = ctr - WA / 2;
    if (wlo < 0) wlo = 0;
    if (wlo > NN - WA) wlo = NN - WA;

    float b0 = FLTMAX, b1 = FLTMAX, b2 = FLTMAX;
    const int lo = wlo + wv * (WA / 8), hi = lo + (WA / 8);
    for (int base = lo; base < hi; base += 64) {
        float4 pv = Ps[base + lane];      // coalesced per-lane tile load
        #pragma unroll 8
        for (int u = 0; u < 64; ++u) {
            float px = bcastf(pv.x, u);
            float py = bcastf(pv.y, u);
            float pz = bcastf(pv.z, u);
            float pw = bcastf(pv.w, u);
            float dd = dist_c(qx, qy, qz, q2, px, py, pz, pw);
            INSV(dd);
        }
    }

    int base = (wv * 64 + lane) * 3;
    sdm[base + 0] = b0; sdm[base + 1] = b1; sdm[base + 2] = b2;
    __syncthreads();

    if (t < 64) {
        #pragma unroll
        for (int w = 1; w < 8; w++) {
            int bb = (w * 64 + t) * 3;
            float e0 = sdm[bb + 0], e1 = sdm[bb + 1], e2 = sdm[bb + 2];
            INSV(e0); INSV(e1); INSV(e2);
        }
        float R = sqrtf(b2 + 1e-3f + 1e-3f * b2) + 1e-3f;
        float lox = qx - R, hix = qx + R;
        #pragma unroll
        for (int mask = 1; mask < 64; mask <<= 1) {
            lox = fminf(lox, __shfl_xor(lox, mask));
            hix = fmaxf(hix, __shfl_xor(hix, mask));
        }
        if (t == 0) {
            grange[g] = make_int2(Bs[xbin(lox)], Bs[xbin(hix) + 1]);
        }
    }
}

// ---------------- kernel 5a: transpose F1,F2 -> Ft, float4 both sides -----
__global__ __launch_bounds__(256) void transpose_f4(
    const float* __restrict__ F1, const float* __restrict__ F2,
    float* __restrict__ Ft)
{
    __shared__ float tile[64][65];
    const int v  = blockIdx.x;            // 0..3071
    const int b  = v / 1536;
    const int r  = v % 1536;
    const int ct = r / 256;               // 0..5
    const int nt = r % 256;               // 0..255
    const int c0 = ct * 64, n0 = nt * 64;
    const int t  = threadIdx.x;
    const int q4 = t & 15;                // float4 index
    const int rr = t >> 4;                // 0..15

    #pragma unroll
    for (int i = 0; i < 4; i++) {
        int cl = i * 16 + rr;
        int c  = c0 + cl;
        const float* src = (c < C1)
            ? (F1 + ((size_t)b * C1 + c) * NN)
            : (F2 + ((size_t)b * C2 + (c - C1)) * NN);
        float4 f = *(const float4*)&src[n0 + q4 * 4];
        tile[cl][q4 * 4 + 0] = f.x;
        tile[cl][q4 * 4 + 1] = f.y;
        tile[cl][q4 * 4 + 2] = f.z;
        tile[cl][q4 * 4 + 3] = f.w;
    }
    __syncthreads();
    #pragma unroll
    for (int i = 0; i < 4; i++) {
        int nl = i * 16 + rr;
        float4 o;
        o.x = tile[q4 * 4 + 0][nl];
        o.y = tile[q4 * 4 + 1][nl];
        o.z = tile[q4 * 4 + 2][nl];
        o.w = tile[q4 * 4 + 3][nl];
        *(float4*)&Ft[((size_t)b * NN + (n0 + nl)) * CF + c0 + q4 * 4] = o;
    }
}

// ---------------- kernel 5b: pruned sweep — tile64 + readlane broadcast ---
// 1024 blocks x 256. wave w = bid*4+wv; g = w>>5, split s = w&31.
// Partials at [split][sorted_slot]: lane-contiguous coalesced writes.
__global__ __launch_bounds__(256) void sweep_knn(
    const float4* __restrict__ P4s, const int* __restrict__ idxs,
    const int2* __restrict__ grange, const int* __restrict__ qperm,
    const float* __restrict__ Q,
    float4* __restrict__ pd, int4* __restrict__ pi)
{
    const int t    = threadIdx.x;
    const int lane = t & 63;
    const int wv   = __builtin_amdgcn_readfirstlane(t >> 6);
    const int w    = blockIdx.x * 4 + wv;  // 0..4095
    const int g    = w >> 5;               // 0..127
    const int s    = w & (NSPL - 1);       // 0..31
    const int b    = g >> 6;
    const int gl   = g & 63;

    const int qi = qperm[b * MM + gl * 64 + lane];
    const float qx = Q[(size_t)b * 3 * MM + qi];
    const float qy = Q[(size_t)b * 3 * MM + MM + qi];
    const float qz = Q[(size_t)b * 3 * MM + 2 * MM + qi];
    const float q2 = __fadd_rn(__fadd_rn(__fmul_rn(qx, qx), __fmul_rn(qy, qy)),
                               __fmul_rn(qz, qz));

    int2 gr = grange[g];
    const int glo = __builtin_amdgcn_readfirstlane(gr.x);
    const int ghi = __builtin_amdgcn_readfirstlane(gr.y);
    const int len = ghi - glo;
    const int chunk = (len + NSPL - 1) / NSPL;
    int lo = glo + s * chunk;
    int hi = lo + chunk; if (hi > ghi) hi = ghi;

    const float4* Ps = P4s  + (size_t)b * NN;
    const int*    Is = idxs + (size_t)b * NN;

    float b0 = FLTMAX, b1 = FLTMAX, b2 = FLTMAX;
    int   i0 = 0x7fffffff, i1 = 0x7fffffff, i2 = 0x7fffffff;

    for (int base = lo; base < hi; base += 64) {
        int cnt = hi - base; if (cnt > 64) cnt = 64;
        float4 pv = make_float4(0.f, 0.f, 0.f, 0.f);
        int    id = 0;
        if (lane < cnt) {                  // coalesced per-lane tile load
            pv = Ps[base + lane];
            id = Is[base + lane];
        }
        for (int u = 0; u < cnt; ++u) {
            float px = bcastf(pv.x, u);
            float py = bcastf(pv.y, u);
            float pz = bcastf(pv.z, u);
            float pw = bcastf(pv.w, u);
            int  pid = __builtin_amdgcn_readlane(id, u);
            float dd = dist_c(qx, qy, qz, q2, px, py, pz, pw);
            INSL(dd, pid);
        }
    }

    // [split][sorted_slot] layout: lane-contiguous -> coalesced store,
    // each cacheline owned by exactly one wave.
    int o = s * (BB * MM) + (b * MM + gl * 64 + lane);
    pd[o] = make_float4(b0, b1, b2, 0.0f);
    pi[o] = make_int4(i0, i1, i2, 0);
}

// ---------------- kernel 6: butterfly merge + interp + pool + write -------
// block = sorted slot; qi = qperm[slot] gives original query index.
__global__ __launch_bounds__(256) void merge_interp_pool(
    const float* __restrict__ P, const float* __restrict__ Q,
    const float* __restrict__ G, const float* __restrict__ Ft,
    const float4* __restrict__ pd, const int4* __restrict__ pi,
    const int* __restrict__ qperm, const float* __restrict__ pg,
    float* __restrict__ out)
{
    __shared__ float agg[392];
    __shared__ float swt[3];
    __shared__ int   sidm[3];

    const int t  = threadIdx.x;
    const int mg = blockIdx.x;            // sorted slot: b*MM + pos
    const int b  = mg >> 12;
    const int m  = qperm[mg];             // original query index (uniform)

    float4* out4 = (float4*)(out + ((size_t)b * MM + m) * MM);

    if (t < 64) {
        const int lane = t;
        float b0 = FLTMAX, b1 = FLTMAX, b2 = FLTMAX;
        int   i0 = 0x7fffffff, i1 = 0x7fffffff, i2 = 0x7fffffff;
        if (lane < NSPL) {
            // lane s reads record [s][mg]: 32 clean lines, MLP 32
            float4 d4 = pd[lane * (BB * MM) + mg];
            int4   i4 = pi[lane * (BB * MM) + mg];
            b0 = d4.x; b1 = d4.y; b2 = d4.z;
            i0 = i4.x; i1 = i4.y; i2 = i4.z;
        }

        #pragma unroll
        for (int mask = 1; mask < NSPL; mask <<= 1) {
            float e0 = __shfl_xor(b0, mask);
            float e1 = __shfl_xor(b1, mask);
            float e2 = __shfl_xor(b2, mask);
            int   j0 = __shfl_xor(i0, mask);
            int   j1 = __shfl_xor(i1, mask);
            int   j2 = __shfl_xor(i2, mask);
            INSL(e0, j0);
            INSL(e1, j1);
            INSL(e2, j2);
        }

        int myid = (lane == 0) ? i0 : ((lane == 1) ? i1 : i2);
        float w = 0.0f;
        if (lane < 3) {
            const float* Pb = P + (size_t)b * 3 * NN;
            float qx = Q[(size_t)b * 3 * MM + m];
            float qy = Q[(size_t)b * 3 * MM + MM + m];
            float qz = Q[(size_t)b * 3 * MM + 2 * MM + m];
            float dx = __fsub_rn(Pb[myid],          qx);
            float dy = __fsub_rn(Pb[NN + myid],     qy);
            float dz = __fsub_rn(Pb[2 * NN + myid], qz);
            float ds = __fadd_rn(__fadd_rn(__fmul_rn(dx, dx), __fmul_rn(dy, dy)),
                                 __fmul_rn(dz, dz));
            w = expf(-0.5f * ds);
        }
        float wA = __shfl(w, 0);
        float wB = __shfl(w, 1);
        float wC = __shfl(w, 2);
        if (lane < 3) {
            float Z = __fadd_rn(__fadd_rn(wA, wB), wC);
            swt[lane]  = w / Z;
            sidm[lane] = myid;
        }
    } else {
        if (t >= 65 && t < 68) {
            agg[t - 65] = Q[(size_t)b * 3 * MM + (size_t)(t - 65) * MM + m];
        }
        if (t == 64) agg[387] = G[(size_t)b * CG];
        const float4* pg4 = (const float4*)(pg + (size_t)b * MM);
        for (int g = t - 64; g < 743; g += 192) {
            out4[281 + g] = pg4[281 + g];
        }
    }
    __syncthreads();

    const int   i0 = sidm[0], i1 = sidm[1], i2 = sidm[2];
    const float w0 = swt[0],  w1 = swt[1],  w2 = swt[2];
    const float* r0 = Ft + ((size_t)b * NN + i0) * CF;
    const float* r1 = Ft + ((size_t)b * NN + i1) * CF;
    const float* r2 = Ft + ((size_t)b * NN + i2) * CF;

    for (int c = t; c < CF; c += 256) {
        float v = __fadd_rn(__fadd_rn(__fmul_rn(r0[c], w0), __fmul_rn(r1[c], w1)),
                            __fmul_rn(r2[c], w2));
        agg[3 + c] = v;
    }
    __syncthreads();

    for (int g = t; g < 281; g += 256) {
        int j0 = g * 4;
        float4 o;
        float* op = &o.x;
        #pragma unroll
        for (int u = 0; u < 4; u++) {
            int j = j0 + u;
            int s = (j * CT) >> 12;
            int e = ((j + 1) * CT + (MM - 1)) >> 12;
            float v = agg[s];
            if (e - s > 1) v = fmaxf(v, agg[s + 1]);
            op[u] = v;
        }
        out4[g] = o;
    }
}

extern "C" void kernel_launch(void* const* d_in, const int* in_sizes, int n_in,
                              void* d_out, int out_size, void* d_ws, size_t ws_size,
                              hipStream_t stream) {
    (void)in_sizes; (void)n_in; (void)out_size;
    const float* P  = (const float*)d_in[0];
    const float* Q  = (const float*)d_in[1];
    const float* F1 = (const float*)d_in[2];
    const float* F2 = (const float*)d_in[3];
    const float* G  = (const float*)d_in[4];
    float* out = (float*)d_out;

    const size_t off_ft    = 0;
    const size_t sz_ft     = (size_t)BB * NN * CF * 4;        // 50,331,648
    const size_t off_p4s   = off_ft + sz_ft;
    const size_t sz_p4s    = (size_t)BB * NN * 16;            // 524,288
    const size_t off_idxs  = off_p4s + sz_p4s;
    const size_t sz_idxs   = (size_t)BB * NN * 4;             // 131,072
    const size_t off_binst = off_idxs + sz_idxs;
    const size_t sz_binst  = 8192;
    const size_t off_ph    = off_binst + sz_binst;
    const size_t sz_ph     = (size_t)BB * NB * 4;
    const size_t off_qh    = off_ph + sz_ph;
    const size_t sz_qh     = (size_t)BB * NB * 4;
    const size_t off_pc    = off_qh + sz_qh;
    const size_t sz_pc     = (size_t)BB * NB * 4;
    const size_t off_qc    = off_pc + sz_pc;
    const size_t sz_qc     = (size_t)BB * NB * 4;
    const size_t off_qperm = off_qc + sz_qc;
    const size_t sz_qperm  = (size_t)BB * MM * 4;
    const size_t off_gr    = off_qperm + sz_qperm;
    const size_t sz_gr     = 128 * 8;
    const size_t off_pd    = off_gr + sz_gr;
    const size_t sz_pd     = (size_t)BB * MM * NSPL * 16;     // 4,194,304
    const size_t off_pi    = off_pd + sz_pd;
    const size_t sz_pi     = sz_pd;
    const size_t off_pg    = off_pi + sz_pi;
    const size_t sz_pg     = (size_t)BB * MM * 4;
    const size_t need      = off_pg + sz_pg;                  // ~60 MB

    if (ws_size >= need) {
        float*  Ft   = (float*)((char*)d_ws + off_ft);
        float4* P4s  = (float4*)((char*)d_ws + off_p4s);
        int*    idxs = (int*)((char*)d_ws + off_idxs);
        int*    bst  = (int*)((char*)d_ws + off_binst);
        int*    ph   = (int*)((char*)d_ws + off_ph);
        int*    qh   = (int*)((char*)d_ws + off_qh);
        int*    pc   = (int*)((char*)d_ws + off_pc);
        int*    qc   = (int*)((char*)d_ws + off_qc);
        int*    qpm  = (int*)((char*)d_ws + off_qperm);
        int2*   gr   = (int2*)((char*)d_ws + off_gr);
        float4* pdb  = (float4*)((char*)d_ws + off_pd);
        int4*   pib  = (int4*)((char*)d_ws + off_pi);
        float*  pg   = (float*)((char*)d_ws + off_pg);

        hipMemsetAsync((char*)d_ws + off_ph, 0, sz_ph + sz_qh, stream);
        hipLaunchKernelGGL(k_hist, dim3(184), dim3(256), 0, stream,
                           P, Q, G, ph, qh, pg);
        hipLaunchKernelGGL(k_scan, dim3(BB), dim3(512), 0, stream,
                           ph, qh, bst, pc, qc);
        hipLaunchKernelGGL(k_scatter, dim3(160), dim3(256), 0, stream,
                           P, Q, pc, qc, P4s, idxs, qpm);
        hipLaunchKernelGGL(stageA, dim3(128), dim3(512), 0, stream,
                           P4s, bst, qpm, Q, gr);
        hipLaunchKernelGGL(transpose_f4, dim3(3072), dim3(256), 0, stream,
                           F1, F2, Ft);
        hipLaunchKernelGGL(sweep_knn, dim3(1024), dim3(256), 0, stream,
                           P4s, idxs, gr, qpm, Q, pdb, pib);
        hipLaunchKernelGGL(merge_interp_pool, dim3(BB * MM), dim3(256), 0, stream,
                           P, Q, G, Ft, pdb, pib, qpm, pg, out);
    } else {
        hipLaunchKernelGGL(p2p_fused, dim3(BB * MM), dim3(256), 0, stream,
                           P, Q, F1, F2, G, out);
    }
}

// Round 12
// 158.987 us; speedup vs baseline: 1.3496x; 1.3496x over previous
//
#include <hip/hip_runtime.h>

#define BB 2
#define NN 16384
#define MM 4096
#define C1 128
#define C2 256
#define CF 384    // C1+C2
#define CG 1024
#define CT 1411   // 3 + 384 + 1024
#define FLTMAX 3.402823466e+38f

#define NB   512               // x-bins
#define XLO  (-4.5f)
#define DXF  0.017578125f      // 9/512, exact in binary
#define INVDX 56.888888889f    // 512/9
#define WA   2048              // stage-A window points (32 x 64 lanes)

// ---------------- fallback (round-1) kernel ----------------
__global__ __launch_bounds__(256) void p2p_fused(
    const float* __restrict__ P, const float* __restrict__ Q,
    const float* __restrict__ F1, const float* __restrict__ F2,
    const float* __restrict__ G, float* __restrict__ out)
{
    const int t  = threadIdx.x;
    const int bm = blockIdx.x;
    const int b  = bm >> 12;
    const int m  = bm & (MM - 1);

    const float* Pb = P + (size_t)b * 3 * NN;
    const float qx = Q[(size_t)b * 3 * MM + 0 * MM + m];
    const float qy = Q[(size_t)b * 3 * MM + 1 * MM + m];
    const float qz = Q[(size_t)b * 3 * MM + 2 * MM + m];
    const float q2 = __fadd_rn(__fadd_rn(__fmul_rn(qx, qx), __fmul_rn(qy, qy)),
                               __fmul_rn(qz, qz));

    float bd0 = FLTMAX, bd1 = FLTMAX, bd2 = FLTMAX;
    int   bi0 = 0x7fffffff, bi1 = 0x7fffffff, bi2 = 0x7fffffff;

    for (int n = t; n < NN; n += 256) {
        float px = Pb[n];
        float py = Pb[NN + n];
        float pz = Pb[2 * NN + n];
        float p2 = __fadd_rn(__fadd_rn(__fmul_rn(px, px), __fmul_rn(py, py)),
                             __fmul_rn(pz, pz));
        float qp = __fadd_rn(__fadd_rn(__fmul_rn(qx, px), __fmul_rn(qy, py)),
                             __fmul_rn(qz, pz));
        float d2 = __fsub_rn(__fadd_rn(q2, p2), __fadd_rn(qp, qp));
        if (d2 < bd2) {
            if (d2 < bd1) {
                if (d2 < bd0) { bd2 = bd1; bi2 = bi1; bd1 = bd0; bi1 = bi0; bd0 = d2; bi0 = n; }
                else          { bd2 = bd1; bi2 = bi1; bd1 = d2;  bi1 = n; }
            } else            { bd2 = d2;  bi2 = n; }
        }
    }

    __shared__ float sd[256][3];
    __shared__ int   si[256][3];
    sd[t][0] = bd0; sd[t][1] = bd1; sd[t][2] = bd2;
    si[t][0] = bi0; si[t][1] = bi1; si[t][2] = bi2;
    __syncthreads();

    for (int off = 128; off >= 1; off >>= 1) {
        if (t < off) {
            float A[3]  = { sd[t][0], sd[t][1], sd[t][2] };
            int   AI[3] = { si[t][0], si[t][1], si[t][2] };
            float Bv[3] = { sd[t + off][0], sd[t + off][1], sd[t + off][2] };
            int   BI[3] = { si[t + off][0], si[t + off][1], si[t + off][2] };
            float rd[3]; int ri[3];
            int pa = 0, pb = 0;
            #pragma unroll
            for (int r = 0; r < 3; r++) {
                bool ta = (A[pa] < Bv[pb]) || (A[pa] == Bv[pb] && AI[pa] < BI[pb]);
                if (ta) { rd[r] = A[pa];  ri[r] = AI[pa]; pa++; }
                else    { rd[r] = Bv[pb]; ri[r] = BI[pb]; pb++; }
            }
            sd[t][0] = rd[0]; sd[t][1] = rd[1]; sd[t][2] = rd[2];
            si[t][0] = ri[0]; si[t][1] = ri[1]; si[t][2] = ri[2];
        }
        __syncthreads();
    }

    __shared__ float wsh[3];
    __shared__ int   ish[3];
    __shared__ float agg[CT + 1];

    if (t == 0) {
        float w[3];
        #pragma unroll
        for (int k = 0; k < 3; k++) {
            int i = si[0][k];
            ish[k] = i;
            float dx = __fsub_rn(Pb[i],          qx);
            float dy = __fsub_rn(Pb[NN + i],     qy);
            float dz = __fsub_rn(Pb[2 * NN + i], qz);
            float ds = __fadd_rn(__fadd_rn(__fmul_rn(dx, dx), __fmul_rn(dy, dy)),
                                 __fmul_rn(dz, dz));
            w[k] = expf(-0.5f * ds);
        }
        float Z = __fadd_rn(__fadd_rn(w[0], w[1]), w[2]);
        wsh[0] = w[0] / Z; wsh[1] = w[1] / Z; wsh[2] = w[2] / Z;
    }
    __syncthreads();

    const int   i0 = ish[0], i1 = ish[1], i2 = ish[2];
    const float w0 = wsh[0], w1 = wsh[1], w2 = wsh[2];

    if (t < 3) agg[t] = (t == 0) ? qx : ((t == 1) ? qy : qz);

    for (int c = t; c < C1 + C2; c += 256) {
        const float* base = (c < C1)
            ? (F1 + ((size_t)b * C1 + c) * NN)
            : (F2 + ((size_t)b * C2 + (c - C1)) * NN);
        float f0 = base[i0], f1 = base[i1], f2 = base[i2];
        float v = __fadd_rn(__fadd_rn(__fmul_rn(f0, w0), __fmul_rn(f1, w1)),
                            __fmul_rn(f2, w2));
        agg[3 + c] = v;
    }
    for (int c = t; c < CG; c += 256) {
        agg[3 + C1 + C2 + c] = G[(size_t)b * CG + c];
    }
    __syncthreads();

    float* orow = out + ((size_t)b * MM + m) * MM;
    for (int j = t; j < MM; j += 256) {
        int s = (j * CT) >> 12;
        int e = ((j + 1) * CT + (MM - 1)) >> 12;
        float v = agg[s];
        if (e - s > 1) v = fmaxf(v, agg[s + 1]);
        orow[j] = v;
    }
}

__device__ __forceinline__ int xbin(float x) {
    int ib = (int)floorf((x - XLO) * INVDX);
    return (ib < 0) ? 0 : ((ib > NB - 1) ? NB - 1 : ib);
}

// ---------------- kernel 1: histograms + pg row ----------------
__global__ __launch_bounds__(256) void k_hist(
    const float* __restrict__ P, const float* __restrict__ Q,
    const float* __restrict__ G,
    int* __restrict__ phist, int* __restrict__ qhist, float* __restrict__ pg)
{
    const int bid = blockIdx.x;
    const int t   = threadIdx.x;
    if (bid < 128) {
        int gid = bid * 256 + t;              // BB*NN
        int b = gid >> 14, n = gid & (NN - 1);
        atomicAdd(&phist[b * NB + xbin(P[(size_t)b * 3 * NN + n])], 1);
    } else if (bid < 160) {
        int gid = (bid - 128) * 256 + t;      // BB*MM
        int b = gid >> 12, m = gid & (MM - 1);
        atomicAdd(&qhist[b * NB + xbin(Q[(size_t)b * 3 * MM + m])], 1);
    } else {
        int gid = (bid - 160) * 256 + t;
        int b  = gid / 2972;
        int jj = gid % 2972;
        if (b < BB) {
            int j = 1124 + jj;
            int s = (j * CT) >> 12;
            int e = ((j + 1) * CT + (MM - 1)) >> 12;
            float v = G[(size_t)b * CG + (s - 387)];
            if (e - s > 1) v = fmaxf(v, G[(size_t)b * CG + (s - 386)]);
            pg[(size_t)b * MM + j] = v;
        }
    }
}

// ---------------- kernel 2: prefix scans -> binst, pcur, qcur -------------
__global__ __launch_bounds__(512) void k_scan(
    const int* __restrict__ phist, const int* __restrict__ qhist,
    int* __restrict__ binst, int* __restrict__ pcur, int* __restrict__ qcur)
{
    __shared__ int s[NB];
    const int b = blockIdx.x;
    const int t = threadIdx.x;

    s[t] = phist[b * NB + t];
    __syncthreads();
    for (int d = 1; d < NB; d <<= 1) {
        int v = (t >= d) ? s[t - d] : 0;
        __syncthreads();
        s[t] += v;
        __syncthreads();
    }
    int excl = s[t] - phist[b * NB + t];
    binst[b * (NB + 1) + t] = excl;
    pcur[b * NB + t] = excl;
    if (t == 0) binst[b * (NB + 1) + NB] = NN;
    __syncthreads();

    s[t] = qhist[b * NB + t];
    __syncthreads();
    for (int d = 1; d < NB; d <<= 1) {
        int v = (t >= d) ? s[t - d] : 0;
        __syncthreads();
        s[t] += v;
        __syncthreads();
    }
    qcur[b * NB + t] = s[t] - qhist[b * NB + t];
}

// ---------------- kernel 3: scatter (points + queries) --------------------
__global__ __launch_bounds__(256) void k_scatter(
    const float* __restrict__ P, const float* __restrict__ Q,
    int* __restrict__ pcur, int* __restrict__ qcur,
    float4* __restrict__ P4s, int* __restrict__ idxs, int* __restrict__ qperm)
{
    const int bid = blockIdx.x;
    const int t   = threadIdx.x;
    if (bid < 128) {
        int gid = bid * 256 + t;
        int b = gid >> 14, n = gid & (NN - 1);
        const float* Pb = P + (size_t)b * 3 * NN;
        float x = Pb[n], y = Pb[NN + n], z = Pb[2 * NN + n];
        float p2 = __fadd_rn(__fadd_rn(__fmul_rn(x, x), __fmul_rn(y, y)),
                             __fmul_rn(z, z));
        int pos = atomicAdd(&pcur[b * NB + xbin(x)], 1);
        P4s[(size_t)b * NN + pos]  = make_float4(x, y, z, p2);
        idxs[(size_t)b * NN + pos] = n;
    } else {
        int gid = (bid - 128) * 256 + t;
        int b = gid >> 12, m = gid & (MM - 1);
        int pos = atomicAdd(&qcur[b * NB + xbin(Q[(size_t)b * 3 * MM + m])], 1);
        qperm[b * MM + pos] = m;
    }
}

// exact-rn distance, identical rounding to the np reference expansion
__device__ __forceinline__ float dist_rn(float qx, float qy, float qz, float q2,
                                         float4 v)
{
    float qp = __fadd_rn(__fadd_rn(__fmul_rn(qx, v.x), __fmul_rn(qy, v.y)),
                         __fmul_rn(qz, v.z));
    return __fsub_rn(__fadd_rn(q2, v.w), __fadd_rn(qp, qp));
}

// value-only branchless 3-min insert (for ub computation)
#define INSV(dv)                                                             \
    {                                                                        \
        bool c0 = (dv) < b0, c1 = (dv) < b1, c2 = (dv) < b2;                 \
        float nb2 = c1 ? b1 : (c2 ? (dv) : b2);                              \
        float nb1 = c0 ? b0 : (c1 ? (dv) : b1);                              \
        float nb0 = c0 ? (dv) : b0;                                          \
        b0 = nb0; b1 = nb1; b2 = nb2;                                        \
    }

// lexicographic (d, idx) branchless insert — order-independent == top_k
#define INSL(dv, nv)                                                         \
    {                                                                        \
        bool c0 = ((dv) < b0) || ((dv) == b0 && (nv) < i0);                  \
        bool c1 = ((dv) < b1) || ((dv) == b1 && (nv) < i1);                  \
        bool c2 = ((dv) < b2) || ((dv) == b2 && (nv) < i2);                  \
        float nb2 = c1 ? b1 : (c2 ? (dv) : b2);                              \
        int   ni2 = c1 ? i1 : (c2 ? (nv) : i2);                              \
        float nb1 = c0 ? b0 : (c1 ? (dv) : b1);                              \
        int   ni1 = c0 ? i0 : (c1 ? (nv) : i1);                              \
        float nb0 = c0 ? (dv) : b0;                                          \
        int   ni0 = c0 ? (nv) : i0;                                          \
        b0 = nb0; b1 = nb1; b2 = nb2; i0 = ni0; i1 = ni1; i2 = ni2;          \
    }

// ---------------- kernel 4: stage A2 — per-query ub + range ---------------
// 2048 blocks x 256 = 8192 waves; ONE WAVE PER QUERY (sorted slot).
// Lanes scan a fixed 2048-pt window (points across lanes, coalesced);
// butterfly allreduce of 3 smallest values -> ub -> conservative range.
__global__ __launch_bounds__(256) void stageA2(
    const float4* __restrict__ P4s, const int* __restrict__ binst,
    const int* __restrict__ qperm, const float* __restrict__ Q,
    int2* __restrict__ qrange)
{
    const int t    = threadIdx.x;
    const int lane = t & 63;
    const int wv   = t >> 6;
    const int slot = blockIdx.x * 4 + wv;   // 0..8191
    const int b    = slot >> 12;

    const int qi = qperm[slot];             // wave-uniform
    const float qx = Q[(size_t)b * 3 * MM + qi];
    const float qy = Q[(size_t)b * 3 * MM + MM + qi];
    const float qz = Q[(size_t)b * 3 * MM + 2 * MM + qi];
    const float q2 = __fadd_rn(__fadd_rn(__fmul_rn(qx, qx), __fmul_rn(qy, qy)),
                               __fmul_rn(qz, qz));

    const float4* Ps = P4s + (size_t)b * NN;
    const int*    Bs = binst + b * (NB + 1);

    int wlo = Bs[xbin(qx)] - WA / 2;
    if (wlo < 0) wlo = 0;
    if (wlo > NN - WA) wlo = NN - WA;

    float b0 = FLTMAX, b1 = FLTMAX, b2 = FLTMAX;
    #pragma unroll 4
    for (int it = 0; it < WA / 64; ++it) {
        float4 pv = Ps[wlo + it * 64 + lane];   // coalesced
        float dd = dist_rn(qx, qy, qz, q2, pv);
        INSV(dd);
    }
    // butterfly allreduce: 3 smallest window values
    #pragma unroll
    for (int mask = 1; mask < 64; mask <<= 1) {
        float e0 = __shfl_xor(b0, mask);
        float e1 = __shfl_xor(b1, mask);
        float e2 = __shfl_xor(b2, mask);
        INSV(e0); INSV(e1); INSV(e2);
    }

    if (lane == 0) {
        // conservative radius: margins >> expanded-form rounding skew
        float R = sqrtf(b2 + 1e-3f + 1e-3f * b2) + 1e-3f;
        int lo = Bs[xbin(qx - R)];
        int hi = Bs[xbin(qx + R) + 1];
        qrange[slot] = make_int2(lo, hi);
    }
}

// ---------------- kernel 5a: transpose F1,F2 -> Ft, float4 both sides -----
__global__ __launch_bounds__(256) void transpose_f4(
    const float* __restrict__ F1, const float* __restrict__ F2,
    float* __restrict__ Ft)
{
    __shared__ float tile[64][65];
    const int v  = blockIdx.x;            // 0..3071
    const int b  = v / 1536;
    const int r  = v % 1536;
    const int ct = r / 256;               // 0..5
    const int nt = r % 256;               // 0..255
    const int c0 = ct * 64, n0 = nt * 64;
    const int t  = threadIdx.x;
    const int q4 = t & 15;                // float4 index
    const int rr = t >> 4;                // 0..15

    #pragma unroll
    for (int i = 0; i < 4; i++) {
        int cl = i * 16 + rr;
        int c  = c0 + cl;
        const float* src = (c < C1)
            ? (F1 + ((size_t)b * C1 + c) * NN)
            : (F2 + ((size_t)b * C2 + (c - C1)) * NN);
        float4 f = *(const float4*)&src[n0 + q4 * 4];
        tile[cl][q4 * 4 + 0] = f.x;
        tile[cl][q4 * 4 + 1] = f.y;
        tile[cl][q4 * 4 + 2] = f.z;
        tile[cl][q4 * 4 + 3] = f.w;
    }
    __syncthreads();
    #pragma unroll
    for (int i = 0; i < 4; i++) {
        int nl = i * 16 + rr;
        float4 o;
        o.x = tile[q4 * 4 + 0][nl];
        o.y = tile[q4 * 4 + 1][nl];
        o.z = tile[q4 * 4 + 2][nl];
        o.w = tile[q4 * 4 + 3][nl];
        *(float4*)&Ft[((size_t)b * NN + (n0 + nl)) * CF + c0 + q4 * 4] = o;
    }
}

// ---------------- kernel 5b: sweep2 — one wave per query, lane-parallel ---
// 2048 blocks x 256 = 8192 waves. Wave scans its query's range with points
// distributed ACROSS lanes (coalesced float4), per-lane lex top-3, butterfly
// merge, lanes 0-2 weights, lane 0 writes rec[qi].
__global__ __launch_bounds__(256) void sweep2(
    const float4* __restrict__ P4s, const int* __restrict__ idxs,
    const int2* __restrict__ qrange, const int* __restrict__ qperm,
    const float* __restrict__ P, const float* __restrict__ Q,
    float* __restrict__ rec)
{
    const int t    = threadIdx.x;
    const int lane = t & 63;
    const int wv   = t >> 6;
    const int slot = blockIdx.x * 4 + wv;   // 0..8191
    const int b    = slot >> 12;

    const int qi = qperm[slot];             // wave-uniform
    const float qx = Q[(size_t)b * 3 * MM + qi];
    const float qy = Q[(size_t)b * 3 * MM + MM + qi];
    const float qz = Q[(size_t)b * 3 * MM + 2 * MM + qi];
    const float q2 = __fadd_rn(__fadd_rn(__fmul_rn(qx, qx), __fmul_rn(qy, qy)),
                               __fmul_rn(qz, qz));

    int2 gr = qrange[slot];                 // wave-uniform
    const int lo = gr.x, hi = gr.y;

    const float4* Ps = P4s  + (size_t)b * NN;
    const int*    Is = idxs + (size_t)b * NN;

    float b0 = FLTMAX, b1 = FLTMAX, b2 = FLTMAX;
    int   i0 = 0x7fffffff, i1 = 0x7fffffff, i2 = 0x7fffffff;

    #pragma unroll 2
    for (int idx = lo + lane; idx < hi; idx += 64) {
        float4 pv = Ps[idx];                // coalesced
        int    id = Is[idx];
        float  dd = dist_rn(qx, qy, qz, q2, pv);
        INSL(dd, id);
    }

    // butterfly allreduce with lexicographic merge (== top_k semantics)
    #pragma unroll
    for (int mask = 1; mask < 64; mask <<= 1) {
        float e0 = __shfl_xor(b0, mask);
        float e1 = __shfl_xor(b1, mask);
        float e2 = __shfl_xor(b2, mask);
        int   j0 = __shfl_xor(i0, mask);
        int   j1 = __shfl_xor(i1, mask);
        int   j2 = __shfl_xor(i2, mask);
        INSL(e0, j0);
        INSL(e1, j1);
        INSL(e2, j2);
    }

    // weights: exact direct-form distance (reference semantics)
    int myid = (lane == 0) ? i0 : ((lane == 1) ? i1 : i2);
    float w = 0.0f;
    if (lane < 3) {
        const float* Pb = P + (size_t)b * 3 * NN;
        float dx = __fsub_rn(Pb[myid],          qx);
        float dy = __fsub_rn(Pb[NN + myid],     qy);
        float dz = __fsub_rn(Pb[2 * NN + myid], qz);
        float ds = __fadd_rn(__fadd_rn(__fmul_rn(dx, dx), __fmul_rn(dy, dy)),
                             __fmul_rn(dz, dz));
        w = expf(-0.5f * ds);
    }
    float wA = __shfl(w, 0);
    float wB = __shfl(w, 1);
    float wC = __shfl(w, 2);
    if (lane == 0) {
        float Z = __fadd_rn(__fadd_rn(wA, wB), wC);
        float* R_ = rec + ((size_t)b * MM + qi) * 8;
        R_[0] = __int_as_float(i0);
        R_[1] = __int_as_float(i1);
        R_[2] = __int_as_float(i2);
        R_[3] = wA / Z;
        R_[4] = wB / Z;
        R_[5] = wC / Z;
    }
}

// ---------------- kernel 6: gather + interp + pool + write (R2-proven) -----
__global__ __launch_bounds__(256) void interp_pool(
    const float* __restrict__ Q, const float* __restrict__ G,
    const float* __restrict__ Ft, const float* __restrict__ rec,
    const float* __restrict__ pg, float* __restrict__ out)
{
    __shared__ float agg[392];
    __shared__ float srec[8];
    const int t  = threadIdx.x;
    const int mg = blockIdx.x;
    const int b  = mg >> 12;
    const int m  = mg & (MM - 1);

    if (t < 8) srec[t] = rec[(size_t)mg * 8 + t];
    if (t == 8) agg[387] = G[(size_t)b * CG];
    if (t < 3) agg[t] = Q[(size_t)b * 3 * MM + (size_t)t * MM + m];
    __syncthreads();

    const int i0 = __float_as_int(srec[0]);
    const int i1 = __float_as_int(srec[1]);
    const int i2 = __float_as_int(srec[2]);
    const float w0 = srec[3], w1 = srec[4], w2 = srec[5];
    const float* r0 = Ft + ((size_t)b * NN + i0) * CF;
    const float* r1 = Ft + ((size_t)b * NN + i1) * CF;
    const float* r2 = Ft + ((size_t)b * NN + i2) * CF;

    for (int c = t; c < CF; c += 256) {
        float v = __fadd_rn(__fadd_rn(__fmul_rn(r0[c], w0), __fmul_rn(r1[c], w1)),
                            __fmul_rn(r2[c], w2));
        agg[3 + c] = v;
    }
    __syncthreads();

    float4* out4 = (float4*)(out + (size_t)mg * MM);
    for (int g = t; g < 281; g += 256) {
        int j0 = g * 4;
        float4 o;
        float* op = &o.x;
        #pragma unroll
        for (int u = 0; u < 4; u++) {
            int j = j0 + u;
            int s = (j * CT) >> 12;
            int e = ((j + 1) * CT + (MM - 1)) >> 12;
            float v = agg[s];
            if (e - s > 1) v = fmaxf(v, agg[s + 1]);
            op[u] = v;
        }
        out4[g] = o;
    }
    const float4* pg4 = (const float4*)(pg + (size_t)b * MM);
    for (int g = t; g < 743; g += 256) {
        out4[281 + g] = pg4[281 + g];
    }
}

extern "C" void kernel_launch(void* const* d_in, const int* in_sizes, int n_in,
                              void* d_out, int out_size, void* d_ws, size_t ws_size,
                              hipStream_t stream) {
    (void)in_sizes; (void)n_in; (void)out_size;
    const float* P  = (const float*)d_in[0];
    const float* Q  = (const float*)d_in[1];
    const float* F1 = (const float*)d_in[2];
    const float* F2 = (const float*)d_in[3];
    const float* G  = (const float*)d_in[4];
    float* out = (float*)d_out;

    const size_t off_ft    = 0;
    const size_t sz_ft     = (size_t)BB * NN * CF * 4;        // 50,331,648
    const size_t off_p4s   = off_ft + sz_ft;
    const size_t sz_p4s    = (size_t)BB * NN * 16;            // 524,288
    const size_t off_idxs  = off_p4s + sz_p4s;
    const size_t sz_idxs   = (size_t)BB * NN * 4;             // 131,072
    const size_t off_binst = off_idxs + sz_idxs;
    const size_t sz_binst  = 8192;
    const size_t off_ph    = off_binst + sz_binst;
    const size_t sz_ph     = (size_t)BB * NB * 4;
    const size_t off_qh    = off_ph + sz_ph;
    const size_t sz_qh     = (size_t)BB * NB * 4;
    const size_t off_pc    = off_qh + sz_qh;
    const size_t sz_pc     = (size_t)BB * NB * 4;
    const size_t off_qc    = off_pc + sz_pc;
    const size_t sz_qc     = (size_t)BB * NB * 4;
    const size_t off_qperm = off_qc + sz_qc;
    const size_t sz_qperm  = (size_t)BB * MM * 4;
    const size_t off_qr    = off_qperm + sz_qperm;
    const size_t sz_qr     = (size_t)BB * MM * 8;             // 65,536
    const size_t off_rec   = off_qr + sz_qr;
    const size_t sz_rec    = (size_t)BB * MM * 8 * 4;         // 262,144
    const size_t off_pg    = off_rec + sz_rec;
    const size_t sz_pg     = (size_t)BB * MM * 4;
    const size_t need      = off_pg + sz_pg;                  // ~52 MB

    if (ws_size >= need) {
        float*  Ft   = (float*)((char*)d_ws + off_ft);
        float4* P4s  = (float4*)((char*)d_ws + off_p4s);
        int*    idxs = (int*)((char*)d_ws + off_idxs);
        int*    bst  = (int*)((char*)d_ws + off_binst);
        int*    ph   = (int*)((char*)d_ws + off_ph);
        int*    qh   = (int*)((char*)d_ws + off_qh);
        int*    pc   = (int*)((char*)d_ws + off_pc);
        int*    qc   = (int*)((char*)d_ws + off_qc);
        int*    qpm  = (int*)((char*)d_ws + off_qperm);
        int2*   qr   = (int2*)((char*)d_ws + off_qr);
        float*  rc   = (float*)((char*)d_ws + off_rec);
        float*  pg   = (float*)((char*)d_ws + off_pg);

        hipMemsetAsync((char*)d_ws + off_ph, 0, sz_ph + sz_qh, stream);
        hipLaunchKernelGGL(k_hist, dim3(184), dim3(256), 0, stream,
                           P, Q, G, ph, qh, pg);
        hipLaunchKernelGGL(k_scan, dim3(BB), dim3(512), 0, stream,
                           ph, qh, bst, pc, qc);
        hipLaunchKernelGGL(k_scatter, dim3(160), dim3(256), 0, stream,
                           P, Q, pc, qc, P4s, idxs, qpm);
        hipLaunchKernelGGL(stageA2, dim3(2048), dim3(256), 0, stream,
                           P4s, bst, qpm, Q, qr);
        hipLaunchKernelGGL(transpose_f4, dim3(3072), dim3(256), 0, stream,
                           F1, F2, Ft);
        hipLaunchKernelGGL(sweep2, dim3(2048), dim3(256), 0, stream,
                           P4s, idxs, qr, qpm, P, Q, rc);
        hipLaunchKernelGGL(interp_pool, dim3(BB * MM), dim3(256), 0, stream,
                           Q, G, Ft, rc, pg, out);
    } else {
        hipLaunchKernelGGL(p2p_fused, dim3(BB * MM), dim3(256), 0, stream,
                           P, Q, F1, F2, G, out);
    }
}